// Round 5
// baseline (371.867 us; speedup 1.0000x reference)
//
#include <hip/hip_runtime.h>

#define NTOK 262144L

typedef __attribute__((ext_vector_type(4))) float f32x4;
typedef __attribute__((ext_vector_type(8))) short bf16x8;   // 8 x bf16 (4 VGPRs)
typedef __attribute__((ext_vector_type(4))) unsigned u32x4;

static __device__ __forceinline__ unsigned short f2bf(float f) {
  unsigned int u = __builtin_bit_cast(unsigned int, f);
  u += 0x7fffu + ((u >> 16) & 1u);          // round-nearest-even
  return (unsigned short)(u >> 16);
}

static __device__ __forceinline__ unsigned cvtpk(float lo, float hi) {
  unsigned r;
  asm("v_cvt_pk_bf16_f32 %0, %1, %2" : "=v"(r) : "v"(lo), "v"(hi));
  return r;
}

// ---- pre-pack all weights fp32 -> bf16 in MFMA B-fragment order ----
// W1 region: [e][kt=16][ct=8][lane=64][j=8]  (k = kt*32 + (lane>>4)*8 + j, col = ct*16 + (lane&15))
// W2 region: [e][kt=4 ][ct=8][lane=64][j=8]
__global__ void pack_w(const float* __restrict__ Wt1, const float* __restrict__ Wa1,
                       const float* __restrict__ Wv1, const float* __restrict__ Wt2,
                       const float* __restrict__ Wa2, const float* __restrict__ Wv2,
                       unsigned short* __restrict__ pk) {
  int idx = blockIdx.x * 256 + threadIdx.x;
  if (idx >= 245760) return;
  float v;
  if (idx < 196608) {
    int j = idx & 7, l = (idx >> 3) & 63, ct = (idx >> 9) & 7, kt = (idx >> 12) & 15, e = idx >> 16;
    const float* W = (e == 0) ? Wt1 : (e == 1) ? Wa1 : Wv1;
    v = W[(kt * 32 + ((l >> 4) * 8) + j) * 128 + ct * 16 + (l & 15)];
  } else {
    int i2 = idx - 196608;
    int j = i2 & 7, l = (i2 >> 3) & 63, ct = (i2 >> 9) & 7, kt = (i2 >> 12) & 3, e = i2 >> 14;
    const float* W = (e == 0) ? Wt2 : (e == 1) ? Wa2 : Wv2;
    v = W[(kt * 32 + ((l >> 4) * 8) + j) * 128 + ct * 16 + (l & 15)];
  }
  pk[idx] = f2bf(v);
}

// Block: 64 rows x 128 cols, 256 thr (4 waves). Wave w: cols [32w,32w+32), rt=4 row-tiles.
// Xs: 64r x 64c bf16 chunk, 128 B/row = 8 slots; physical slot = logical ^ (row&7).
// H:  64r x 128c bf16, 256 B/row = 16 slots; physical slot = logical ^ (row&7).

__global__ __launch_bounds__(256, 3) void mlp3(
    const float* __restrict__ X, const unsigned short* __restrict__ pk,
    const float* __restrict__ bt1, const float* __restrict__ bt2,
    const float* __restrict__ ba1, const float* __restrict__ ba2,
    const float* __restrict__ bv1, const float* __restrict__ bv2,
    float* __restrict__ out) {
  __shared__ unsigned short Xs[2 * 64 * 64];   // 16 KiB dbuf
  __shared__ unsigned short H0[64 * 128];      // 16 KiB
  __shared__ unsigned short H1[64 * 128];      // 16 KiB
  const int t = threadIdx.x;
  const long brow = (long)blockIdx.x * 64;
  const int lane = t & 63;
  const int w = t >> 6;
  const int l15 = lane & 15;
  const int g = lane >> 4;
  char* const xs = (char*)Xs;

  // staging map: thread -> (row, 16-col segment)
  const int srow = t >> 2;           // 0..63
  const int sseg = t & 3;            // 0..3
  const float* __restrict__ sgp = X + (brow + srow) * 512 + sseg * 16;
  const int wbyte0 = srow * 128 + ((((2 * sseg)) ^ (srow & 7)) << 4);
  const int wbyte1 = srow * 128 + ((((2 * sseg + 1)) ^ (srow & 7)) << 4);

  // ---- layer-1 accumulators, 3 experts, rt=4 x ct=2 ----
  f32x4 at[4][2], aa[4][2], av[4][2];
  #pragma unroll
  for (int c = 0; c < 2; ++c) {
    float b0 = bt1[(2 * w + c) * 16 + l15];
    float b1v = ba1[(2 * w + c) * 16 + l15];
    float b2v = bv1[(2 * w + c) * 16 + l15];
    #pragma unroll
    for (int rt = 0; rt < 4; ++rt) {
      at[rt][c] = (f32x4){b0, b0, b0, b0};
      aa[rt][c] = (f32x4){b1v, b1v, b1v, b1v};
      av[rt][c] = (f32x4){b2v, b2v, b2v, b2v};
    }
  }

  // ---- stage chunk 0 into buf0 ----
  {
    f32x4 q0 = *(const f32x4*)(sgp + 0);
    f32x4 q1 = *(const f32x4*)(sgp + 4);
    f32x4 q2 = *(const f32x4*)(sgp + 8);
    f32x4 q3 = *(const f32x4*)(sgp + 12);
    u32x4 p0 = {cvtpk(q0[0], q0[1]), cvtpk(q0[2], q0[3]), cvtpk(q1[0], q1[1]), cvtpk(q1[2], q1[3])};
    u32x4 p1 = {cvtpk(q2[0], q2[1]), cvtpk(q2[2], q2[3]), cvtpk(q3[0], q3[1]), cvtpk(q3[2], q3[3])};
    *(u32x4*)(xs + wbyte0) = p0;
    *(u32x4*)(xs + wbyte1) = p1;
  }
  __syncthreads();

  unsigned fmask = 0;   // bit rt*4+r: flag != 0 for row rt*16+4g+r

  // per-thread ds_read address components (swizzle keys fold to l15&7)
  const int abase = l15 * 128;                  // + rt*2048 (imm) + slotx
  const int sx0 = ((0 * 4 + g) ^ (l15 & 7)) << 4;
  const int sx1 = ((1 * 4 + g) ^ (l15 & 7)) << 4;

  // ---- fused layer-1: 8 chunks of K=64 (2 kt each) ----
  #pragma unroll 2
  for (int kc = 0; kc < 8; ++kc) {
    const bool st = kc < 7;
    f32x4 q0, q1, q2, q3;
    if (st) {   // T14: issue next chunk's global loads early
      const float* gp = sgp + (kc + 1) * 64;
      q0 = *(const f32x4*)(gp + 0);
      q1 = *(const f32x4*)(gp + 4);
      q2 = *(const f32x4*)(gp + 8);
      q3 = *(const f32x4*)(gp + 12);
    }
    const char* xb = xs + ((kc & 1) << 13);
    __builtin_amdgcn_s_setprio(1);
    #pragma unroll
    for (int ktl = 0; ktl < 2; ++ktl) {
      const int kt = kc * 2 + ktl;
      const int wo = ((kt * 8 + 2 * w) << 9) + (lane << 3);
      bf16x8 wt0 = *(const bf16x8*)(pk + wo);
      bf16x8 wt1v = *(const bf16x8*)(pk + wo + 512);
      bf16x8 wa0 = *(const bf16x8*)(pk + 65536 + wo);
      bf16x8 wa1v = *(const bf16x8*)(pk + 65536 + wo + 512);
      bf16x8 wv0 = *(const bf16x8*)(pk + 131072 + wo);
      bf16x8 wv1v = *(const bf16x8*)(pk + 131072 + wo + 512);
      const int sx = ktl ? sx1 : sx0;
      #pragma unroll
      for (int rt = 0; rt < 4; ++rt) {
        bf16x8 a = *(const bf16x8*)(xb + abase + rt * 2048 + sx);
        at[rt][0] = __builtin_amdgcn_mfma_f32_16x16x32_bf16(a, wt0, at[rt][0], 0, 0, 0);
        at[rt][1] = __builtin_amdgcn_mfma_f32_16x16x32_bf16(a, wt1v, at[rt][1], 0, 0, 0);
        aa[rt][0] = __builtin_amdgcn_mfma_f32_16x16x32_bf16(a, wa0, aa[rt][0], 0, 0, 0);
        aa[rt][1] = __builtin_amdgcn_mfma_f32_16x16x32_bf16(a, wa1v, aa[rt][1], 0, 0, 0);
        av[rt][0] = __builtin_amdgcn_mfma_f32_16x16x32_bf16(a, wv0, av[rt][0], 0, 0, 0);
        av[rt][1] = __builtin_amdgcn_mfma_f32_16x16x32_bf16(a, wv1v, av[rt][1], 0, 0, 0);
      }
    }
    __builtin_amdgcn_s_setprio(0);
    if (kc == 7) {
      // routing flags: global col 511 -> chunk 7 (buf1), logical slot 7, byte 14
      #pragma unroll
      for (int rt = 0; rt < 4; ++rt)
        #pragma unroll
        for (int r = 0; r < 4; ++r) {
          int row = rt * 16 + 4 * g + r;
          unsigned short fv = *(const unsigned short*)(xs + 8192 + row * 128 +
                               ((7 ^ (row & 7)) << 4) + 14);
          if (fv != 0) fmask |= 1u << (rt * 4 + r);
        }
    }
    if (st) {   // write-late into the other buffer (its old contents fully consumed)
      char* xw = xs + (((kc + 1) & 1) << 13);
      u32x4 p0 = {cvtpk(q0[0], q0[1]), cvtpk(q0[2], q0[3]), cvtpk(q1[0], q1[1]), cvtpk(q1[2], q1[3])};
      u32x4 p1 = {cvtpk(q2[0], q2[1]), cvtpk(q2[2], q2[3]), cvtpk(q3[0], q3[1]), cvtpk(q3[2], q3[3])};
      *(u32x4*)(xw + wbyte0) = p0;
      *(u32x4*)(xw + wbyte1) = p1;
    }
    __syncthreads();
  }

  // ---- relu + write hidden tiles t -> H0, a -> H1 ----
  #pragma unroll
  for (int rt = 0; rt < 4; ++rt)
    #pragma unroll
    for (int c = 0; c < 2; ++c)
      #pragma unroll
      for (int r = 0; r < 4; ++r) {
        int row = rt * 16 + 4 * g + r;
        int slot = (4 * w + 2 * c + (l15 >> 3)) ^ (row & 7);
        int addr = row * 256 + (slot << 4) + (l15 & 7) * 2;
        *(unsigned short*)((char*)H0 + addr) = f2bf(fmaxf(at[rt][c][r], 0.f));
        *(unsigned short*)((char*)H1 + addr) = f2bf(fmaxf(aa[rt][c][r], 0.f));
      }
  __syncthreads();

  // ---- layer 2 ----
  const int hbase = l15 * 256;                 // + rt*4096 (imm) + hslot(kt)
  auto layer2 = [&](const unsigned short* Hb, int e, const float* __restrict__ b2,
                    f32x4 a2[4][2]) {
    #pragma unroll
    for (int c = 0; c < 2; ++c) {
      float bv = b2[(2 * w + c) * 16 + l15];
      #pragma unroll
      for (int rt = 0; rt < 4; ++rt) a2[rt][c] = (f32x4){bv, bv, bv, bv};
    }
    const unsigned short* W2f = pk + 196608 + e * 16384;
    __builtin_amdgcn_s_setprio(1);
    #pragma unroll
    for (int kt = 0; kt < 4; ++kt) {
      const int wo = ((kt * 8 + 2 * w) << 9) + (lane << 3);
      bf16x8 w0 = *(const bf16x8*)(W2f + wo);
      bf16x8 w1 = *(const bf16x8*)(W2f + wo + 512);
      const int hs = ((kt * 4 + g) ^ (l15 & 7)) << 4;
      #pragma unroll
      for (int rt = 0; rt < 4; ++rt) {
        bf16x8 a = *(const bf16x8*)((const char*)Hb + hbase + rt * 4096 + hs);
        a2[rt][0] = __builtin_amdgcn_mfma_f32_16x16x32_bf16(a, w0, a2[rt][0], 0, 0, 0);
        a2[rt][1] = __builtin_amdgcn_mfma_f32_16x16x32_bf16(a, w1, a2[rt][1], 0, 0, 0);
      }
    }
    __builtin_amdgcn_s_setprio(0);
  };

  f32x4 keep[4][2], a2[4][2];
  layer2(H0, 0, bt2, keep);    // transform
  layer2(H1, 1, ba2, a2);      // actor
  #pragma unroll
  for (int rt = 0; rt < 4; ++rt)
    #pragma unroll
    for (int c = 0; c < 2; ++c)
      #pragma unroll
      for (int r = 0; r < 4; ++r)
        if ((fmask >> (rt * 4 + r)) & 1u) keep[rt][c][r] = a2[rt][c][r];
  __syncthreads();             // layer-2 t/a reads of H0/H1 done -> H0 reusable

  // ---- value head hidden + layer 2 ----
  #pragma unroll
  for (int rt = 0; rt < 4; ++rt)
    #pragma unroll
    for (int c = 0; c < 2; ++c)
      #pragma unroll
      for (int r = 0; r < 4; ++r) {
        int row = rt * 16 + 4 * g + r;
        int slot = (4 * w + 2 * c + (l15 >> 3)) ^ (row & 7);
        int addr = row * 256 + (slot << 4) + (l15 & 7) * 2;
        *(unsigned short*)((char*)H0 + addr) = f2bf(fmaxf(av[rt][c][r], 0.f));
      }
  __syncthreads();
  layer2(H0, 2, bv2, a2);      // value

  // ---- batched stores ----
  float* __restrict__ ov = out + NTOK * 128;
  #pragma unroll
  for (int rt = 0; rt < 4; ++rt)
    #pragma unroll
    for (int c = 0; c < 2; ++c)
      #pragma unroll
      for (int r = 0; r < 4; ++r) {
        long row = brow + rt * 16 + 4 * g + r;
        long col = (2 * w + c) * 16 + l15;
        out[row * 128 + col] = keep[rt][c][r];
        ov[row * 128 + col] = fmaxf(a2[rt][c][r], 0.f);
      }
}

extern "C" void kernel_launch(void* const* d_in, const int* in_sizes, int n_in,
                              void* d_out, int out_size, void* d_ws, size_t ws_size,
                              hipStream_t stream) {
  const float* X   = (const float*)d_in[0];
  const float* Wt1 = (const float*)d_in[1];
  const float* bt1 = (const float*)d_in[2];
  const float* Wt2 = (const float*)d_in[3];
  const float* bt2 = (const float*)d_in[4];
  const float* Wa1 = (const float*)d_in[5];
  const float* ba1 = (const float*)d_in[6];
  const float* Wa2 = (const float*)d_in[7];
  const float* ba2 = (const float*)d_in[8];
  const float* Wv1 = (const float*)d_in[9];
  const float* bv1 = (const float*)d_in[10];
  const float* Wv2 = (const float*)d_in[11];
  const float* bv2 = (const float*)d_in[12];
  unsigned short* pk = (unsigned short*)d_ws;   // 245760 bf16 = 480 KiB packed weights

  pack_w<<<960, 256, 0, stream>>>(Wt1, Wa1, Wv1, Wt2, Wa2, Wv2, pk);
  mlp3<<<4096, 256, 0, stream>>>(X, pk, bt1, bt2, ba1, ba2, bv1, bv2, (float*)d_out);
}